// Round 4
// baseline (234.147 us; speedup 1.0000x reference)
//
#include <hip/hip_runtime.h>

// ConvLSTM cell on MI355X (gfx950) — round 4.
// Implicit GEMM M=256 (4 gates x 64 oc), K=864 (96ch x 9 taps), N=131072.
// bf16 MFMA 32x32x16. Block = one og-group (M=64 = 4 gates x 16 oc) with its
// ENTIRE A slice (108 KB) resident in LDS (staged once, ONE barrier), then a
// barrier-free K-loop: A via ds_read_b128, B direct-global (coalesced P'),
// 1-deep software pipeline over kk. Lane-local LSTM epilogue.

#define B_   32
#define CIN  32
#define HC_  64
#define HH   64
#define WW   64

#define OG_SLAB (9 * 2 * 6 * 64 * 8)     // 55296 shorts = 108 KB per og
#define A_ELEMS (4 * OG_SLAB)            // 221184 bf16 = 256 x 864 packed A
#define P_ROW   (12 * 66 * 8)            // shorts per P' row = 6336

typedef __attribute__((ext_vector_type(8)))  short  short8;
typedef __attribute__((ext_vector_type(16))) float  floatx16;

struct PackArgs {
    const float* wx[4]; const float* wh[4];
    const float* bx[4]; const float* bh[4];
};

__device__ __forceinline__ short f2bf(float f) {
    unsigned u = __float_as_uint(f);
    u += 0x7FFFu + ((u >> 16) & 1u);     // round-to-nearest-even
    return (short)(u >> 16);
}

__device__ __forceinline__ void gl_lds16(const short* g, short* l) {
    __builtin_amdgcn_global_load_lds(
        (const __attribute__((address_space(1))) unsigned int*)g,
        (__attribute__((address_space(3))) unsigned int*)l, 16, 0, 0);
}

// ---- pack A: [og 4][tap 9][fi 2][kk 6][lane 64][j 8] -----------------------
// m32 = lane&31 ; gate = 2*fi + (m32>>4) ; oc = og*16 + (m32&15)
// c = kk*16 + (lane>>5)*8 + j   (A-operand: m = lane&31, k = (lane>>5)*8+j)
__global__ __launch_bounds__(256) void pack_weights(PackArgs pa, short* a_pk, float* bias) {
    int idx = blockIdx.x * 256 + threadIdx.x;
    if (idx < A_ELEMS) {
        int j    = idx & 7;
        int lane = (idx >> 3) & 63;
        int rest = idx >> 9;             // ((og*9+tap)*2+fi)*6 + kk
        int kk   = rest % 6;
        int r2   = rest / 6;
        int fi   = r2 & 1;
        int r3   = r2 >> 1;
        int tap  = r3 % 9;
        int og   = r3 / 9;
        int m32 = lane & 31;
        int gate = 2 * fi + (m32 >> 4);
        int oc   = og * 16 + (m32 & 15);
        int c    = kk * 16 + (lane >> 5) * 8 + j;
        int ky = tap / 3, kx = tap - 3 * ky;
        float v = (c < CIN)
            ? pa.wx[gate][((oc * CIN + c) * 3 + ky) * 3 + kx]
            : pa.wh[gate][((oc * HC_ + (c - CIN)) * 3 + ky) * 3 + kx];
        a_pk[idx] = f2bf(v);
    }
    if (idx < 256) {
        int gate = idx >> 6, oc = idx & 63;
        bias[idx] = pa.bx[gate][oc] + pa.bh[gate][oc];
    }
}

// ---- pack x||h -> P'[b][yy][pc 12][xx 66][8ch] bf16, zero borders ----------
__global__ __launch_bounds__(256) void pack_input(const float* __restrict__ x,
                                                  const float* __restrict__ h,
                                                  short* __restrict__ P) {
    const int yy = blockIdx.x, b = blockIdx.y;
    int4* prow4 = (int4*)(P + ((size_t)b * 66 + yy) * P_ROW);  // 792 chunks

    if (yy == 0 || yy == 65) {
        int4 z = {0, 0, 0, 0};
        for (int g = threadIdx.x; g < 792; g += 256) prow4[g] = z;
        return;
    }

    __shared__ short t[64 * 98];                     // [x][c], pad 96->98
    const int y = yy - 1;
    const int col = threadIdx.x & 63, cg = threadIdx.x >> 6;
    for (int c = cg; c < 96; c += 4) {
        float v = (c < CIN) ? x[((b * CIN + c) * HH + y) * WW + col]
                            : h[((b * HC_ + (c - CIN)) * HH + y) * WW + col];
        t[col * 98 + c] = f2bf(v);
    }
    __syncthreads();

    for (int g = threadIdx.x; g < 792; g += 256) {   // pc = g/66, xx = g%66
        int pc = g / 66, xx = g - 66 * pc;
        int4 val = {0, 0, 0, 0};
        if (xx >= 1 && xx <= 64) {
            const short* sp = &t[(xx - 1) * 98 + pc * 8];
            val.x = *(const int*)(sp + 0); val.y = *(const int*)(sp + 2);
            val.z = *(const int*)(sp + 4); val.w = *(const int*)(sp + 6);
        }
        prow4[g] = val;
    }
}

// ---- main: grid 1024 = og(4) x b(32) x rowgroup(8 of 8 rows) ---------------
// blockIdx = og*256 + b*8 + rg  (idx%8 = rg -> og-blocks sharing B rows land
// on the same XCD). 512 thr = 8 waves; wave wv owns row y = rg*8+wv, M=64.
__global__ __launch_bounds__(512, 2) void convlstm_main(
    const short* __restrict__ P, const short* __restrict__ a_pk,
    const float* __restrict__ bias, const float* __restrict__ cell,
    float* __restrict__ out)
{
    __shared__ __align__(16) short As[OG_SLAB];      // 108 KB -> 1 block/CU

    const int tid = threadIdx.x;
    const int og = blockIdx.x >> 8;
    const int b  = (blockIdx.x >> 3) & 31;
    const int rg = blockIdx.x & 7;

    const int wv = tid >> 6, lane = tid & 63;
    const int ln31 = lane & 31, hg = lane >> 5;
    const int y = rg * 8 + wv;

    // ---- stage this og's full A (6912 16B-chunks), one barrier -------------
    {
        const short* src = a_pk + og * OG_SLAB;
        #pragma unroll
        for (int i = 0; i < 14; ++i) {
            int id = i * 512 + tid;
            if (id < 6912)
                gl_lds16(src + id * 8, As + (i * 512 + wv * 64) * 8);
        }
    }
    __syncthreads();

    floatx16 acc[2][2];
    #pragma unroll
    for (int fi = 0; fi < 2; ++fi)
        #pragma unroll
        for (int ns = 0; ns < 2; ++ns)
            #pragma unroll
            for (int q = 0; q < 16; ++q) acc[fi][ns][q] = 0.f;

    const int albase = lane * 8;                     // A per-lane LDS offset
    const int lnoff  = (hg * 66 + ln31) * 8;         // B per-lane offset

    for (int ky = 0; ky < 3; ++ky) {
        const short* Brow = P + ((size_t)(b * 66) + y + ky) * P_ROW + lnoff;
        // B chunk offset (shorts): kk*1056 + kx*8 + ns*256
        short8 bf[2][3][2];
        #pragma unroll
        for (int kx = 0; kx < 3; ++kx)
            #pragma unroll
            for (int ns = 0; ns < 2; ++ns)
                bf[0][kx][ns] = *(const short8*)&Brow[kx * 8 + ns * 256];

        #pragma unroll
        for (int kk = 0; kk < 6; ++kk) {
            const int cur = kk & 1, nxt = cur ^ 1;
            if (kk < 5) {
                #pragma unroll
                for (int kx = 0; kx < 3; ++kx)
                    #pragma unroll
                    for (int ns = 0; ns < 2; ++ns)
                        bf[nxt][kx][ns] =
                            *(const short8*)&Brow[(kk + 1) * 1056 + kx * 8 + ns * 256];
            }
            #pragma unroll
            for (int kx = 0; kx < 3; ++kx) {
                const int tap = ky * 3 + kx;
                short8 a0 = *(const short8*)&As[((tap * 2 + 0) * 6 + kk) * 512 + albase];
                short8 a1 = *(const short8*)&As[((tap * 2 + 1) * 6 + kk) * 512 + albase];
                acc[0][0] = __builtin_amdgcn_mfma_f32_32x32x16_bf16(a0, bf[cur][kx][0], acc[0][0], 0, 0, 0);
                acc[0][1] = __builtin_amdgcn_mfma_f32_32x32x16_bf16(a0, bf[cur][kx][1], acc[0][1], 0, 0, 0);
                acc[1][0] = __builtin_amdgcn_mfma_f32_32x32x16_bf16(a1, bf[cur][kx][0], acc[1][0], 0, 0, 0);
                acc[1][1] = __builtin_amdgcn_mfma_f32_32x32x16_bf16(a1, bf[cur][kx][1], acc[1][1], 0, 0, 0);
            }
        }
    }

    // ---- lane-local LSTM epilogue ------------------------------------------
    // C/D 32x32 map: col = ln31, row r32 = (r&3) + 4*hg + 8*(r>>2).
    // acc[fi][.] rows: r32<16 -> gate 2fi, oc16=r32 ; r32>=16 -> gate 2fi+1.
    const size_t plane = (size_t)B_ * HC_ * HH * WW;
    #pragma unroll
    for (int q = 0; q < 4; ++q)
    #pragma unroll
    for (int b8 = 0; b8 < 2; ++b8) {
        const int oc16 = q + 4 * hg + 8 * b8;
        const int oc = og * 16 + oc16;
        const float Bi = bias[oc],       Bf = bias[64 + oc];
        const float Bo = bias[128 + oc], Bg = bias[192 + oc];
        const int r_lo = q + 4 * b8, r_hi = q + 4 * (2 + b8);
        #pragma unroll
        for (int ns = 0; ns < 2; ++ns) {
            float zi = acc[0][ns][r_lo] + Bi;
            float zf = acc[0][ns][r_hi] + Bf;
            float zo = acc[1][ns][r_lo] + Bo;
            float zg = acc[1][ns][r_hi] + Bg;
            float ig = 1.f / (1.f + __expf(-zi));
            float fg = 1.f / (1.f + __expf(-zf));
            float sg = 1.f / (1.f + __expf(-zo));
            float e2 = __expf(2.f * zg);
            float gg = 1.f - 2.f / (e2 + 1.f);               // tanh(zg)
            const int x = ns * 32 + ln31;
            size_t off = ((size_t)(b * HC_ + oc) * HH + y) * WW + x;
            float cn = fg * cell[off] + ig * gg;
            float ec = __expf(2.f * cn);
            out[off] = sg * (1.f - 2.f / (ec + 1.f));        // h_new
            out[plane + off] = cn;                           // c_new
        }
    }
}

extern "C" void kernel_launch(void* const* d_in, const int* in_sizes, int n_in,
                              void* d_out, int out_size, void* d_ws, size_t ws_size,
                              hipStream_t stream) {
    PackArgs pa;
    pa.wx[0] = (const float*)d_in[3];  pa.bx[0] = (const float*)d_in[4];
    pa.wx[1] = (const float*)d_in[5];  pa.bx[1] = (const float*)d_in[6];
    pa.wx[2] = (const float*)d_in[7];  pa.bx[2] = (const float*)d_in[8];
    pa.wx[3] = (const float*)d_in[9];  pa.bx[3] = (const float*)d_in[10];
    pa.wh[0] = (const float*)d_in[11]; pa.bh[0] = (const float*)d_in[12];
    pa.wh[1] = (const float*)d_in[13]; pa.bh[1] = (const float*)d_in[14];
    pa.wh[2] = (const float*)d_in[15]; pa.bh[2] = (const float*)d_in[16];
    pa.wh[3] = (const float*)d_in[17]; pa.bh[3] = (const float*)d_in[18];

    short* a_pk = (short*)d_ws;                                    // 442368 B
    float* bias = (float*)((char*)d_ws + A_ELEMS * sizeof(short)); // 1024 B
    short* P    = (short*)((char*)d_ws + 443392);                  // 26.76 MB

    pack_weights<<<dim3(A_ELEMS / 256), dim3(256), 0, stream>>>(pa, a_pk, bias);
    pack_input <<<dim3(66, B_), dim3(256), 0, stream>>>(
        (const float*)d_in[0], (const float*)d_in[1], P);
    convlstm_main<<<dim3(1024), dim3(512), 0, stream>>>(
        P, a_pk, bias, (const float*)d_in[2], (float*)d_out);
}